// Round 1
// baseline (228.127 us; speedup 1.0000x reference)
//
#include <hip/hip_runtime.h>
#include <hip/hip_bf16.h>
#include <stdint.h>

#define S_LEN  2048
#define DMODEL 1024
#define NHEADS 16
#define DKH    64
#define NBATCH 2
#define NROWS  (NBATCH * S_LEN)   // 4096
#define NBH    (NBATCH * NHEADS)  // 32

typedef unsigned short ushort_t;
typedef __attribute__((ext_vector_type(8))) short bf16x8;
typedef __attribute__((ext_vector_type(4))) float f32x4;
typedef __attribute__((ext_vector_type(4))) unsigned short us4;

__device__ __forceinline__ ushort_t f2bf(float f) {
  union { float f; unsigned int u; } c; c.f = f;
  unsigned int r = c.u + 0x7FFFu + ((c.u >> 16) & 1u);
  return (ushort_t)(r >> 16);
}

__device__ __forceinline__ void gload_lds16(const void* g, void* l) {
  __builtin_amdgcn_global_load_lds((const __attribute__((address_space(1))) void*)g,
                                   (__attribute__((address_space(3))) void*)l, 16, 0, 0);
}

// ---------------- fp32 -> bf16 cast ----------------
__global__ void cast_kernel(const float* __restrict__ src, ushort_t* __restrict__ dst, int n) {
  int i = (blockIdx.x * blockDim.x + threadIdx.x) * 4;
  if (i >= n) return;
  const float4 v = *(const float4*)(src + i);
  us4 o;
  o.x = f2bf(v.x); o.y = f2bf(v.y); o.z = f2bf(v.z); o.w = f2bf(v.w);
  *(us4*)(dst + i) = o;
}

// ---------------- GEMM: C[M,N] = A[M,K] * B[N,K]^T (bf16 in, fp32 acc) ----------------
// MODE 0: bf16 row-major out (used for V^T)
// MODE 1: fp32 row-major out (final projection)
// MODE 2: RoPE + (B,H,S,dk) bf16 out (Q,K projections)
template<int MODE>
__global__ __launch_bounds__(256, 2)
void gemm_bt(const ushort_t* __restrict__ A, const ushort_t* __restrict__ Bm,
             void* __restrict__ Cp, int M, int N, int K)
{
  __shared__ ushort_t As[128 * 32];
  __shared__ ushort_t Bs[128 * 32];
  const int tid  = threadIdx.x;
  const int lane = tid & 63;
  const int w    = tid >> 6;
  const int wr   = (w >> 1) * 64;
  const int wc   = (w & 1) * 64;
  const int g    = lane >> 4;
  const int lr   = lane & 15;
  const int r0   = blockIdx.y * 128;
  const int c0   = blockIdx.x * 128;

  f32x4 acc[4][4] = {};

  const int idx0 = tid, idx1 = 256 + tid;
  const int row0 = idx0 >> 2, ce0 = (idx0 & 3) * 8;
  const int row1 = idx1 >> 2, ce1 = (idx1 & 3) * 8;

  for (int k0 = 0; k0 < K; k0 += 32) {
    gload_lds16(A  + (size_t)(r0 + row0) * K + k0 + ce0, As + idx0 * 8);
    gload_lds16(A  + (size_t)(r0 + row1) * K + k0 + ce1, As + idx1 * 8);
    gload_lds16(Bm + (size_t)(c0 + row0) * K + k0 + ce0, Bs + idx0 * 8);
    gload_lds16(Bm + (size_t)(c0 + row1) * K + k0 + ce1, Bs + idx1 * 8);
    __syncthreads();
    bf16x8 af[4], bfr[4];
    #pragma unroll
    for (int i = 0; i < 4; i++) {
      af[i]  = *(const bf16x8*)(As + (wr + i * 16 + lr) * 32 + g * 8);
      bfr[i] = *(const bf16x8*)(Bs + (wc + i * 16 + lr) * 32 + g * 8);
    }
    #pragma unroll
    for (int mf = 0; mf < 4; mf++)
      #pragma unroll
      for (int nf = 0; nf < 4; nf++)
        acc[mf][nf] = __builtin_amdgcn_mfma_f32_16x16x32_bf16(af[mf], bfr[nf], acc[mf][nf], 0, 0, 0);
    __syncthreads();
  }

  #pragma unroll
  for (int mf = 0; mf < 4; mf++) {
    #pragma unroll
    for (int nf = 0; nf < 4; nf++) {
      #pragma unroll
      for (int r = 0; r < 4; r++) {
        const int row = r0 + wr + mf * 16 + g * 4 + r;
        const int col = c0 + wc + nf * 16 + lr;
        float v = acc[mf][nf][r];
        if constexpr (MODE == 0) {
          ((ushort_t*)Cp)[(size_t)row * N + col] = f2bf(v);
        } else if constexpr (MODE == 1) {
          ((float*)Cp)[(size_t)row * N + col] = v;
        } else {
          // RoPE: partner element is the adjacent column = adjacent lane
          float pv = __shfl_xor(v, 1);
          const int pos = row & (S_LEN - 1);
          const int d   = col & (DKH - 1);
          const int pr  = d >> 1;
          const float inv = exp2f((float)pr * -0.41524100952f); // -(2/64)*log2(10000)
          const float ang = (float)pos * inv;
          float sn, cs;
          __sincosf(ang, &sn, &cs);
          const float outv = (d & 1) ? (pv * sn + v * cs) : (v * cs - pv * sn);
          const int b = row >> 11, s = row & (S_LEN - 1);
          const int h = col >> 6;
          ((ushort_t*)Cp)[(((size_t)(b * NHEADS + h)) * S_LEN + s) * DKH + d] = f2bf(outv);
        }
      }
    }
  }
}

// ---------------- causal flash attention ----------------
// Q,K: (BH, S, 64) bf16 ; VT: (1024 = h*64+d, 4096 = b*2048+s) bf16
// Out: (B, S, 1024) bf16
__global__ __launch_bounds__(256, 2)
void attn_kernel(const ushort_t* __restrict__ Q, const ushort_t* __restrict__ Kh,
                 const ushort_t* __restrict__ VT, ushort_t* __restrict__ Out)
{
  __shared__ ushort_t Ks[64 * 72];
  __shared__ ushort_t Vs[64 * 72];
  __shared__ ushort_t Ps[4][16 * 72];
  const int tid  = threadIdx.x;
  const int lane = tid & 63;
  const int w    = tid >> 6;
  const int g    = lane >> 4, lr = lane & 15;
  const int bh   = blockIdx.y;
  const int b    = bh >> 4, h = bh & 15;
  const int qt   = (int)gridDim.x - 1 - (int)blockIdx.x;  // longest-first
  const int q0   = qt * 64;
  const int qrow = q0 + w * 16;

  bf16x8 qf0, qf1;
  {
    const ushort_t* qb = Q + ((size_t)bh * S_LEN + qrow + lr) * DKH;
    qf0 = *(const bf16x8*)(qb + g * 8);
    qf1 = *(const bf16x8*)(qb + 32 + g * 8);
  }
  f32x4 o[4] = {};
  float mrun[4], lsum[4];
  #pragma unroll
  for (int r = 0; r < 4; r++) { mrun[r] = -3.0e38f; lsum[r] = 0.f; }

  const int srow0 = tid >> 3,         spc0 = (tid & 7) * 8;
  const int srow1 = (256 + tid) >> 3, spc1 = ((256 + tid) & 7) * 8;

  const ushort_t* Kbase = Kh + (size_t)bh * S_LEN * DKH;
  const ushort_t* Vbase = VT + (size_t)h * DKH * (size_t)NROWS + (size_t)b * S_LEN;

  for (int t = 0; t <= qt; t++) {
    const int kv0 = t * 64;
    *(bf16x8*)(Ks + srow0 * 72 + spc0) = *(const bf16x8*)(Kbase + (size_t)(kv0 + srow0) * DKH + spc0);
    *(bf16x8*)(Ks + srow1 * 72 + spc1) = *(const bf16x8*)(Kbase + (size_t)(kv0 + srow1) * DKH + spc1);
    *(bf16x8*)(Vs + srow0 * 72 + spc0) = *(const bf16x8*)(Vbase + (size_t)srow0 * NROWS + kv0 + spc0);
    *(bf16x8*)(Vs + srow1 * 72 + spc1) = *(const bf16x8*)(Vbase + (size_t)srow1 * NROWS + kv0 + spc1);
    __syncthreads();

    // S = Q K^T
    f32x4 s4[4];
    #pragma unroll
    for (int nf = 0; nf < 4; nf++) {
      bf16x8 b0 = *(const bf16x8*)(Ks + (nf * 16 + lr) * 72 + g * 8);
      bf16x8 b1 = *(const bf16x8*)(Ks + (nf * 16 + lr) * 72 + 32 + g * 8);
      f32x4 z = {};
      z = __builtin_amdgcn_mfma_f32_16x16x32_bf16(qf0, b0, z, 0, 0, 0);
      z = __builtin_amdgcn_mfma_f32_16x16x32_bf16(qf1, b1, z, 0, 0, 0);
      s4[nf] = z;
    }
    // scale + causal mask
    #pragma unroll
    for (int nf = 0; nf < 4; nf++) {
      const int kv = kv0 + nf * 16 + lr;
      #pragma unroll
      for (int r = 0; r < 4; r++) {
        const float v = s4[nf][r] * 0.125f;
        const int q = qrow + g * 4 + r;
        s4[nf][r] = (kv > q) ? -3.0e38f : v;
      }
    }
    // online softmax stats (rows live in (g*4+r), cols across 16 lanes)
    float sc[4];
    #pragma unroll
    for (int r = 0; r < 4; r++) {
      float v = fmaxf(fmaxf(s4[0][r], s4[1][r]), fmaxf(s4[2][r], s4[3][r]));
      v = fmaxf(v, __shfl_xor(v, 1));
      v = fmaxf(v, __shfl_xor(v, 2));
      v = fmaxf(v, __shfl_xor(v, 4));
      v = fmaxf(v, __shfl_xor(v, 8));
      const float mn = fmaxf(mrun[r], v);
      sc[r] = __expf(mrun[r] - mn);
      mrun[r] = mn;
      lsum[r] *= sc[r];
    }
    // P = exp(S - m), per-lane partial row sums, stash P in per-wave LDS
    #pragma unroll
    for (int nf = 0; nf < 4; nf++) {
      #pragma unroll
      for (int r = 0; r < 4; r++) {
        const float p = __expf(s4[nf][r] - mrun[r]);
        lsum[r] += p;
        Ps[w][(g * 4 + r) * 72 + nf * 16 + lr] = f2bf(p);
      }
    }
    // rescale accumulator
    #pragma unroll
    for (int nf = 0; nf < 4; nf++)
      #pragma unroll
      for (int r = 0; r < 4; r++) o[nf][r] *= sc[r];
    // O += P V  (V^T rows give contiguous-kv B fragments)
    #pragma unroll
    for (int kf = 0; kf < 2; kf++) {
      const bf16x8 pA = *(const bf16x8*)(&Ps[w][lr * 72 + kf * 32 + g * 8]);
      #pragma unroll
      for (int nf = 0; nf < 4; nf++) {
        const bf16x8 vB = *(const bf16x8*)(Vs + (nf * 16 + lr) * 72 + kf * 32 + g * 8);
        o[nf] = __builtin_amdgcn_mfma_f32_16x16x32_bf16(pA, vB, o[nf], 0, 0, 0);
      }
    }
    __syncthreads();
  }

  #pragma unroll
  for (int r = 0; r < 4; r++) {
    float v = lsum[r];
    v += __shfl_xor(v, 1);
    v += __shfl_xor(v, 2);
    v += __shfl_xor(v, 4);
    v += __shfl_xor(v, 8);
    lsum[r] = 1.0f / v;
  }
  #pragma unroll
  for (int nf = 0; nf < 4; nf++) {
    #pragma unroll
    for (int r = 0; r < 4; r++) {
      const int s = qrow + g * 4 + r;
      const float v = o[nf][r] * lsum[r];
      Out[((size_t)b * S_LEN + s) * DMODEL + h * DKH + nf * 16 + lr] = f2bf(v);
    }
  }
}

extern "C" void kernel_launch(void* const* d_in, const int* in_sizes, int n_in,
                              void* d_out, int out_size, void* d_ws, size_t ws_size,
                              hipStream_t stream)
{
  const float* x  = (const float*)d_in[0];
  const float* wq = (const float*)d_in[1];
  const float* wk = (const float*)d_in[2];
  const float* wv = (const float*)d_in[3];
  const float* wo = (const float*)d_in[4];
  float* out = (float*)d_out;
  ushort_t* ws = (ushort_t*)d_ws;

  ushort_t* xb  = ws;                                  // 4096x1024  (also reused for attn out)
  ushort_t* wqb = xb  + (size_t)NROWS * DMODEL;
  ushort_t* wkb = wqb + (size_t)DMODEL * DMODEL;
  ushort_t* wvb = wkb + (size_t)DMODEL * DMODEL;
  ushort_t* wob = wvb + (size_t)DMODEL * DMODEL;
  ushort_t* qb  = wob + (size_t)DMODEL * DMODEL;       // (BH,S,64)
  ushort_t* kb  = qb  + (size_t)NROWS * DMODEL;        // (BH,S,64)
  ushort_t* vtb = kb  + (size_t)NROWS * DMODEL;        // (1024,4096) = V^T
  ushort_t* ab  = xb;                                  // attn out aliases xb (x dead by then)

  cast_kernel<<<4096, 256, 0, stream>>>(x,  xb,  NROWS * DMODEL);
  cast_kernel<<<1024, 256, 0, stream>>>(wq, wqb, DMODEL * DMODEL);
  cast_kernel<<<1024, 256, 0, stream>>>(wk, wkb, DMODEL * DMODEL);
  cast_kernel<<<1024, 256, 0, stream>>>(wv, wvb, DMODEL * DMODEL);
  cast_kernel<<<1024, 256, 0, stream>>>(wo, wob, DMODEL * DMODEL);

  dim3 blk(256);
  // Q,K projections with fused RoPE -> (BH,S,64)
  gemm_bt<2><<<dim3(8, 32), blk, 0, stream>>>(xb, wqb, qb, NROWS, DMODEL, DMODEL);
  gemm_bt<2><<<dim3(8, 32), blk, 0, stream>>>(xb, wkb, kb, NROWS, DMODEL, DMODEL);
  // V^T = Wv * X^T  (same GEMM, operands swapped)
  gemm_bt<0><<<dim3(32, 8), blk, 0, stream>>>(wvb, xb, vtb, DMODEL, NROWS, DMODEL);
  // causal flash attention
  attn_kernel<<<dim3(32, 32), blk, 0, stream>>>(qb, kb, vtb, ab);
  // output projection -> fp32
  gemm_bt<1><<<dim3(8, 32), blk, 0, stream>>>(ab, wob, out, NROWS, DMODEL, DMODEL);
}

// Round 2
// 154.046 us; speedup vs baseline: 1.4809x; 1.4809x over previous
//
#include <hip/hip_runtime.h>
#include <hip/hip_bf16.h>
#include <stdint.h>

#define S_LEN  2048
#define DMODEL 1024
#define NHEADS 16
#define DKH    64
#define NBATCH 2
#define NROWS  (NBATCH * S_LEN)   // 4096
#define NBH    (NBATCH * NHEADS)  // 32
#define KVS    72                 // K/V LDS row stride (ushorts)
#define PSTR   68                 // P LDS row stride (ushorts) — write-conflict-free

typedef unsigned short ushort_t;
typedef __attribute__((ext_vector_type(8))) short bf16x8;
typedef __attribute__((ext_vector_type(4))) float f32x4;
typedef __attribute__((ext_vector_type(4))) unsigned short us4;

__device__ __forceinline__ ushort_t f2bf(float f) {
  union { float f; unsigned int u; } c; c.f = f;
  unsigned int r = c.u + 0x7FFFu + ((c.u >> 16) & 1u);
  return (ushort_t)(r >> 16);
}

__device__ __forceinline__ void gload_lds16(const void* g, void* l) {
  __builtin_amdgcn_global_load_lds((const __attribute__((address_space(1))) void*)g,
                                   (__attribute__((address_space(3))) void*)l, 16, 0, 0);
}

// ---------------- fp32 -> bf16 casts ----------------
__global__ void cast_kernel(const float* __restrict__ src, ushort_t* __restrict__ dst, int n) {
  int i = (blockIdx.x * blockDim.x + threadIdx.x) * 4;
  if (i >= n) return;
  const float4 v = *(const float4*)(src + i);
  us4 o;
  o.x = f2bf(v.x); o.y = f2bf(v.y); o.z = f2bf(v.z); o.w = f2bf(v.w);
  *(us4*)(dst + i) = o;
}

// 4 weight matrices (1M elems each) -> one contiguous bf16 buffer
__global__ void cast4_kernel(const float* __restrict__ a, const float* __restrict__ b,
                             const float* __restrict__ c, const float* __restrict__ d,
                             ushort_t* __restrict__ dst) {
  const int i = (blockIdx.x * 256 + threadIdx.x) * 4;
  const int sel = i >> 20;                      // uniform per block
  const float* src = (sel == 0) ? a : (sel == 1) ? b : (sel == 2) ? c : d;
  const float4 v = *(const float4*)(src + (i & ((1 << 20) - 1)));
  us4 o;
  o.x = f2bf(v.x); o.y = f2bf(v.y); o.z = f2bf(v.z); o.w = f2bf(v.w);
  *(us4*)(dst + i) = o;
}

// ---------------- GEMM: C[M,N] = A[M,K] * B[N,K]^T (bf16 in, fp32 acc) ----------------
// MODE 0: bf16 row-major out (used for V^T)
// MODE 1: fp32 row-major out (final projection)
// MODE 2: RoPE + (B,H,S,dk) bf16 out; cols [0,1024) -> Cp (Q), [1024,2048) -> Cp2 (K)
template<int MODE>
__global__ __launch_bounds__(256, 2)
void gemm_bt(const ushort_t* __restrict__ A, const ushort_t* __restrict__ Bm,
             void* __restrict__ Cp, void* __restrict__ Cp2, int M, int N, int K)
{
  __shared__ ushort_t As[128 * 32];
  __shared__ ushort_t Bs[128 * 32];
  const int tid  = threadIdx.x;
  const int lane = tid & 63;
  const int w    = tid >> 6;
  const int wr   = (w >> 1) * 64;
  const int wc   = (w & 1) * 64;
  const int g    = lane >> 4;
  const int lr   = lane & 15;
  const int r0   = blockIdx.y * 128;
  const int c0   = blockIdx.x * 128;

  f32x4 acc[4][4] = {};

  const int idx0 = tid, idx1 = 256 + tid;
  const int row0 = idx0 >> 2, ce0 = (idx0 & 3) * 8;
  const int row1 = idx1 >> 2, ce1 = (idx1 & 3) * 8;

  for (int k0 = 0; k0 < K; k0 += 32) {
    gload_lds16(A  + (size_t)(r0 + row0) * K + k0 + ce0, As + idx0 * 8);
    gload_lds16(A  + (size_t)(r0 + row1) * K + k0 + ce1, As + idx1 * 8);
    gload_lds16(Bm + (size_t)(c0 + row0) * K + k0 + ce0, Bs + idx0 * 8);
    gload_lds16(Bm + (size_t)(c0 + row1) * K + k0 + ce1, Bs + idx1 * 8);
    __syncthreads();
    bf16x8 af[4], bfr[4];
    #pragma unroll
    for (int i = 0; i < 4; i++) {
      af[i]  = *(const bf16x8*)(As + (wr + i * 16 + lr) * 32 + g * 8);
      bfr[i] = *(const bf16x8*)(Bs + (wc + i * 16 + lr) * 32 + g * 8);
    }
    #pragma unroll
    for (int mf = 0; mf < 4; mf++)
      #pragma unroll
      for (int nf = 0; nf < 4; nf++)
        acc[mf][nf] = __builtin_amdgcn_mfma_f32_16x16x32_bf16(af[mf], bfr[nf], acc[mf][nf], 0, 0, 0);
    __syncthreads();
  }

  #pragma unroll
  for (int mf = 0; mf < 4; mf++) {
    #pragma unroll
    for (int nf = 0; nf < 4; nf++) {
      #pragma unroll
      for (int r = 0; r < 4; r++) {
        const int row = r0 + wr + mf * 16 + g * 4 + r;
        const int col = c0 + wc + nf * 16 + lr;
        float v = acc[mf][nf][r];
        if constexpr (MODE == 0) {
          ((ushort_t*)Cp)[(size_t)row * N + col] = f2bf(v);
        } else if constexpr (MODE == 1) {
          ((float*)Cp)[(size_t)row * N + col] = v;
        } else {
          // RoPE: partner element is the adjacent column = adjacent lane
          float pv = __shfl_xor(v, 1);
          const int cc  = col & (DMODEL - 1);
          const int pos = row & (S_LEN - 1);
          const int d   = cc & (DKH - 1);
          const int pr  = d >> 1;
          const float inv = exp2f((float)pr * -0.41524100952f); // -(2/64)*log2(10000)
          const float ang = (float)pos * inv;
          float sn, cs;
          __sincosf(ang, &sn, &cs);
          const float outv = (d & 1) ? (pv * sn + v * cs) : (v * cs - pv * sn);
          const int b = row >> 11, s = row & (S_LEN - 1);
          const int h = cc >> 6;
          ushort_t* dst = (ushort_t*)((col < DMODEL) ? Cp : Cp2);
          dst[(((size_t)(b * NHEADS + h)) * S_LEN + s) * DKH + d] = f2bf(outv);
        }
      }
    }
  }
}

// ---------------- causal flash attention ----------------
// Q,K: (BH, S, 64) bf16 ; VT: (1024 = h*64+d, 4096 = b*2048+s) bf16
// Out: (B, S, 1024) bf16
// Block (x, bh) processes q-tiles {31-x, x} sequentially: exactly 33 kv-iters/block.
// K/V double-buffered in LDS; next tile's global loads issued before compute (T14).
__global__ __launch_bounds__(256, 2)
void attn_kernel(const ushort_t* __restrict__ Q, const ushort_t* __restrict__ Kh,
                 const ushort_t* __restrict__ VT, ushort_t* __restrict__ Out)
{
  __shared__ ushort_t Ks[2][64 * KVS];
  __shared__ ushort_t Vs[2][64 * KVS];
  __shared__ ushort_t Ps[4][16 * PSTR];
  const int tid  = threadIdx.x;
  const int lane = tid & 63;
  const int w    = tid >> 6;
  const int g    = lane >> 4, lr = lane & 15;
  const int bh   = blockIdx.y;
  const int b    = bh >> 4, h = bh & 15;

  const ushort_t* Kbase = Kh + (size_t)bh * S_LEN * DKH;
  const ushort_t* Vbase = VT + (size_t)h * DKH * (size_t)NROWS + (size_t)b * S_LEN;

  const int krow = tid >> 3;        // 0..31
  const int kcol = (tid & 7) * 8;   // 0..56

  bf16x8 kr0, kr1, vr0, vr1;

  for (int half = 0; half < 2; half++) {
    const int qt   = half ? (int)blockIdx.x : (31 - (int)blockIdx.x);
    const int qrow = qt * 64 + w * 16;

    bf16x8 qf0, qf1;
    {
      const ushort_t* qp = Q + ((size_t)bh * S_LEN + qrow + lr) * DKH;
      qf0 = *(const bf16x8*)(qp + g * 8);
      qf1 = *(const bf16x8*)(qp + 32 + g * 8);
    }
    f32x4 o[4] = {};
    float mrun[4], lsum[4];
    #pragma unroll
    for (int r = 0; r < 4; r++) { mrun[r] = -3.0e38f; lsum[r] = 0.f; }

    // prologue: tile 0 -> regs; barrier (prev half's readers done); regs -> buf0
    kr0 = *(const bf16x8*)(Kbase + (size_t)krow * DKH + kcol);
    kr1 = *(const bf16x8*)(Kbase + (size_t)(32 + krow) * DKH + kcol);
    vr0 = *(const bf16x8*)(Vbase + (size_t)krow * NROWS + kcol);
    vr1 = *(const bf16x8*)(Vbase + (size_t)(32 + krow) * NROWS + kcol);
    __syncthreads();
    *(bf16x8*)(Ks[0] + krow * KVS + kcol) = kr0;
    *(bf16x8*)(Ks[0] + (32 + krow) * KVS + kcol) = kr1;
    *(bf16x8*)(Vs[0] + krow * KVS + kcol) = vr0;
    *(bf16x8*)(Vs[0] + (32 + krow) * KVS + kcol) = vr1;

    for (int t = 0; t <= qt; t++) {
      const int cur = t & 1;
      __syncthreads();   // buf[cur] writes visible to all waves
      if (t < qt) {      // issue next tile's global loads; latency hidden by compute
        const int kv0n = (t + 1) * 64;
        kr0 = *(const bf16x8*)(Kbase + (size_t)(kv0n + krow) * DKH + kcol);
        kr1 = *(const bf16x8*)(Kbase + (size_t)(kv0n + 32 + krow) * DKH + kcol);
        vr0 = *(const bf16x8*)(Vbase + (size_t)krow * NROWS + kv0n + kcol);
        vr1 = *(const bf16x8*)(Vbase + (size_t)(32 + krow) * NROWS + kv0n + kcol);
      }

      // S = Q K^T
      f32x4 s4[4];
      __builtin_amdgcn_s_setprio(1);
      #pragma unroll
      for (int nf = 0; nf < 4; nf++) {
        bf16x8 b0 = *(const bf16x8*)(Ks[cur] + (nf * 16 + lr) * KVS + g * 8);
        bf16x8 b1 = *(const bf16x8*)(Ks[cur] + (nf * 16 + lr) * KVS + 32 + g * 8);
        f32x4 z = {};
        z = __builtin_amdgcn_mfma_f32_16x16x32_bf16(qf0, b0, z, 0, 0, 0);
        z = __builtin_amdgcn_mfma_f32_16x16x32_bf16(qf1, b1, z, 0, 0, 0);
        s4[nf] = z;
      }
      __builtin_amdgcn_s_setprio(0);

      // scale (+ causal mask on the diagonal tile only)
      if (t == qt) {
        #pragma unroll
        for (int nf = 0; nf < 4; nf++) {
          const int kv = t * 64 + nf * 16 + lr;
          #pragma unroll
          for (int r = 0; r < 4; r++) {
            const float v = s4[nf][r] * 0.125f;
            s4[nf][r] = (kv > qrow + g * 4 + r) ? -3.0e38f : v;
          }
        }
      } else {
        #pragma unroll
        for (int nf = 0; nf < 4; nf++)
          #pragma unroll
          for (int r = 0; r < 4; r++) s4[nf][r] *= 0.125f;
      }

      // online softmax stats (rows in (g*4+r), cols across 16 lr lanes)
      float sc[4];
      #pragma unroll
      for (int r = 0; r < 4; r++) {
        float v = fmaxf(fmaxf(s4[0][r], s4[1][r]), fmaxf(s4[2][r], s4[3][r]));
        v = fmaxf(v, __shfl_xor(v, 1));
        v = fmaxf(v, __shfl_xor(v, 2));
        v = fmaxf(v, __shfl_xor(v, 4));
        v = fmaxf(v, __shfl_xor(v, 8));
        const float mn = fmaxf(mrun[r], v);
        sc[r] = __expf(mrun[r] - mn);
        mrun[r] = mn;
        lsum[r] *= sc[r];
      }
      // P = exp(S - m); per-lane partial row sums; stash P in per-wave LDS
      #pragma unroll
      for (int nf = 0; nf < 4; nf++) {
        #pragma unroll
        for (int r = 0; r < 4; r++) {
          const float p = __expf(s4[nf][r] - mrun[r]);
          lsum[r] += p;
          Ps[w][(g * 4 + r) * PSTR + nf * 16 + lr] = f2bf(p);
        }
      }
      // rescale accumulator
      #pragma unroll
      for (int nf = 0; nf < 4; nf++)
        #pragma unroll
        for (int r = 0; r < 4; r++) o[nf][r] *= sc[r];

      // O += P V
      __builtin_amdgcn_s_setprio(1);
      #pragma unroll
      for (int kf = 0; kf < 2; kf++) {
        const bf16x8 pA = *(const bf16x8*)(&Ps[w][lr * PSTR + kf * 32 + g * 8]);
        #pragma unroll
        for (int nf = 0; nf < 4; nf++) {
          const bf16x8 vB = *(const bf16x8*)(Vs[cur] + (nf * 16 + lr) * KVS + kf * 32 + g * 8);
          o[nf] = __builtin_amdgcn_mfma_f32_16x16x32_bf16(pA, vB, o[nf], 0, 0, 0);
        }
      }
      __builtin_amdgcn_s_setprio(0);

      if (t < qt) {  // write prefetched tile into the other buffer
        const int nxt = cur ^ 1;
        *(bf16x8*)(Ks[nxt] + krow * KVS + kcol) = kr0;
        *(bf16x8*)(Ks[nxt] + (32 + krow) * KVS + kcol) = kr1;
        *(bf16x8*)(Vs[nxt] + krow * KVS + kcol) = vr0;
        *(bf16x8*)(Vs[nxt] + (32 + krow) * KVS + kcol) = vr1;
      }
    }

    #pragma unroll
    for (int r = 0; r < 4; r++) {
      float v = lsum[r];
      v += __shfl_xor(v, 1);
      v += __shfl_xor(v, 2);
      v += __shfl_xor(v, 4);
      v += __shfl_xor(v, 8);
      lsum[r] = 1.0f / v;
    }
    #pragma unroll
    for (int nf = 0; nf < 4; nf++) {
      #pragma unroll
      for (int r = 0; r < 4; r++) {
        const int s = qrow + g * 4 + r;
        const float v = o[nf][r] * lsum[r];
        Out[((size_t)b * S_LEN + s) * DMODEL + h * DKH + nf * 16 + lr] = f2bf(v);
      }
    }
  }
}

extern "C" void kernel_launch(void* const* d_in, const int* in_sizes, int n_in,
                              void* d_out, int out_size, void* d_ws, size_t ws_size,
                              hipStream_t stream)
{
  const float* x  = (const float*)d_in[0];
  const float* wq = (const float*)d_in[1];
  const float* wk = (const float*)d_in[2];
  const float* wv = (const float*)d_in[3];
  const float* wo = (const float*)d_in[4];
  float* out = (float*)d_out;
  ushort_t* ws = (ushort_t*)d_ws;

  ushort_t* xb  = ws;                                  // 4096x1024  (reused for attn out)
  ushort_t* wqb = xb  + (size_t)NROWS * DMODEL;        // wq,wk,wv,wo contiguous
  ushort_t* wkb = wqb + (size_t)DMODEL * DMODEL;
  ushort_t* wvb = wkb + (size_t)DMODEL * DMODEL;
  ushort_t* wob = wvb + (size_t)DMODEL * DMODEL;
  ushort_t* qb  = wob + (size_t)DMODEL * DMODEL;       // (BH,S,64)
  ushort_t* kb  = qb  + (size_t)NROWS * DMODEL;        // (BH,S,64)
  ushort_t* vtb = kb  + (size_t)NROWS * DMODEL;        // (1024,4096) = V^T
  ushort_t* ab  = xb;                                  // attn out aliases xb

  cast_kernel<<<4096, 256, 0, stream>>>(x, xb, NROWS * DMODEL);
  cast4_kernel<<<4096, 256, 0, stream>>>(wq, wk, wv, wo, wqb);

  dim3 blk(256);
  // Q,K projections fused: N=2048 over [wq;wk], RoPE epilogue -> qb / kb
  gemm_bt<2><<<dim3(16, 32), blk, 0, stream>>>(xb, wqb, qb, kb, NROWS, 2 * DMODEL, DMODEL);
  // V^T = Wv * X^T
  gemm_bt<0><<<dim3(32, 8), blk, 0, stream>>>(wvb, xb, vtb, nullptr, DMODEL, NROWS, DMODEL);
  // causal flash attention (paired q-tiles, 33 iters/block)
  attn_kernel<<<dim3(16, 32), blk, 0, stream>>>(qb, kb, vtb, ab);
  // output projection -> fp32
  gemm_bt<1><<<dim3(8, 32), blk, 0, stream>>>(ab, wob, out, nullptr, NROWS, DMODEL, DMODEL);
}